// Round 6
// baseline (7333.231 us; speedup 1.0000x reference)
//
#include <hip/hip_runtime.h>

// LSTMDynamics v19: B=64, T=512, D_IN=64, H=512, D_OUT=32.
// FUSED-LAYER, XCD-LOCAL groups. v18 post-mortem: the pacer was the serial
// sys-scope L0->L1 cross-XCD edge (sys h0 stores + MALL drain + sys flag +
// sys poll + sys loads), once per step. v19 removes it structurally:
//
//   Block (mt,jt) computes BOTH layers: iteration s does L0 step s (reads
//   h0[s-1]) AND L1 step s-1 (reads h0[s-1], h1[s-2]) — both consume only
//   previous-iteration data -> ONE group exchange per iteration, and all
//   communication stays inside group (mt) = 32 blocks = one XCD (fast path).
//   NO sys-scope access anywhere in the time loop.
//
// Mapping: workers = blocks with sel=blk&7 < 4: mt=sel, jt=blk>>3 (0..31).
// Round-robin dispatch (xcd=blk%8, measured) puts group mt on XCD mt.
// Runtime-verified (v18's proven XCC_ID ballot); sys-scope fallback if not.
// Blocks sel>=4 exit immediately (128 worker blocks x 512 thr = 65536 =
// exactly the epilogue thread count).
//
// Per block: 8 waves. K-split: L0 18 chunks (waves 0,1: 3; waves 2-7: 2),
// L1 32 chunks (4/wave; waves 0-3 read h0, waves 4-7 read h1). Per iter:
//   phase1: wave0 polls f0>=s, wave1 polls f1>=s (overlapped)  [barrier A]
//   phase3: all waves MFMA L0 partials -> red0[w], L1 partials -> red1[w]
//   [barrier B]
//   phase5: wave0: reduce red0 + L0 gates + store h0 (agent) + drain + f0=s+1
//           wave1: reduce red1 + L1 gates + store h1 (agent) + drain + f1=s+1
// Barrier A of iter s+1 separates phase-5 LDS reads from next phase-3 writes.
//
// Dependency algebra (flag = last-completed-iter + 1):
//   iter s reads h0[s-1] (f0>=s), h1[s-2] (f1>=s: wave1 stored h1[s-2] at
//   iter s-1). Anti-deps: ring0 slot s&1 kills h0[s-2], read at iter s-1 by
//   L0 and L1 -> f0,f1>=s covers (flags publish after phase-3 + barrier B).
//   ring1 slot (s-1)&1 kills h1[s-3], read at iter s-1 -> same. 2 slots each.
//   Epilogue: h1[T-1] -> sys h1fin copy (stored at iter T_, drained by its
//   vmcnt(0)) + per-group sys fin flag after the loop.

#define T_    512
#define B_    64
#define H_    512
#define DIN_  64
#define NBLK  256
#define NTHR  512
#define SLOT  (B_ * H_)   // 32768 fp32 per ring slot, layout [b][k]
#define LINE  64          // dwords per flag line (256B)

typedef _Float16 half8  __attribute__((ext_vector_type(8)));
typedef float    floatx4 __attribute__((ext_vector_type(4)));

__device__ inline float sigf(float x) { return 1.f / (1.f + __expf(-x)); }
__device__ inline float tanhf_(float x) {
    if (x >  9.f) return  1.f;
    if (x < -9.f) return -1.f;
    const float e = __expf(2.f * x);
    return (e - 1.f) / (e + 1.f);
}
__device__ inline float4 ld4(const float* p) { return *(const float4*)p; }

// fp32[8] -> fp16 MFMA fragment, normal cached path (weights, x).
__device__ inline half8 frag8(const float* p) {
    const float4 a = ld4(p), b = ld4(p + 4);
    half8 r;
    r[0] = (_Float16)a.x; r[1] = (_Float16)a.y; r[2] = (_Float16)a.z; r[3] = (_Float16)a.w;
    r[4] = (_Float16)b.x; r[5] = (_Float16)b.y; r[6] = (_Float16)b.z; r[7] = (_Float16)b.w;
    return r;
}
__device__ inline half8 frag8_agt(const float* p) {
    float v[8];
    #pragma unroll
    for (int i = 0; i < 8; ++i)
        v[i] = __hip_atomic_load(p + i, __ATOMIC_RELAXED, __HIP_MEMORY_SCOPE_AGENT);
    half8 r;
    #pragma unroll
    for (int i = 0; i < 8; ++i) r[i] = (_Float16)v[i];
    return r;
}
__device__ inline half8 frag8_sys(const float* p) {
    float v[8];
    #pragma unroll
    for (int i = 0; i < 8; ++i)
        v[i] = __hip_atomic_load(p + i, __ATOMIC_RELAXED, __HIP_MEMORY_SCOPE_SYSTEM);
    half8 r;
    #pragma unroll
    for (int i = 0; i < 8; ++i) r[i] = (_Float16)v[i];
    return r;
}
__device__ inline float ld_sys_f(const float* p) {
    return __hip_atomic_load(p, __ATOMIC_RELAXED, __HIP_MEMORY_SCOPE_SYSTEM);
}
__device__ inline void st_sys(float* p, float v) {
    __hip_atomic_store(p, v, __ATOMIC_RELAXED, __HIP_MEMORY_SCOPE_SYSTEM);
}
__device__ inline void st_agt(float* p, float v) {
    __hip_atomic_store(p, v, __ATOMIC_RELAXED, __HIP_MEMORY_SCOPE_AGENT);
}
__device__ inline void st_sys_u(unsigned* p, unsigned v) {
    __hip_atomic_store(p, v, __ATOMIC_RELAXED, __HIP_MEMORY_SCOPE_SYSTEM);
}
__device__ inline void st_agt_u(unsigned* p, unsigned v) {
    __hip_atomic_store(p, v, __ATOMIC_RELAXED, __HIP_MEMORY_SCOPE_AGENT);
}
__device__ inline unsigned ld_sys_u(const unsigned* p) {
    return __hip_atomic_load(p, __ATOMIC_RELAXED, __HIP_MEMORY_SCOPE_SYSTEM);
}
__device__ inline unsigned ld_agt_u(const unsigned* p) {
    return __hip_atomic_load(p, __ATOMIC_RELAXED, __HIP_MEMORY_SCOPE_AGENT);
}

// Wave-parallel flag wait: 64 lanes read flags[lane&31] (one 128B line),
// exit when every producer's flag >= tgt.
__device__ inline void wait_agt(unsigned* line, unsigned tgt, int lane) {
    for (;;) {
        const unsigned v = ld_agt_u(line + (lane & 31));
        if (__all((int)(v >= tgt))) return;
        __builtin_amdgcn_s_sleep(1);
    }
}
__device__ inline void wait_sys(unsigned* line, unsigned tgt, int lane) {
    for (;;) {
        const unsigned v = ld_sys_u(line + (lane & 31));
        if (__all((int)(v >= tgt))) return;
        __builtin_amdgcn_s_sleep(1);
    }
}

// MFMA 16x16x32 f16 fragment layout (proven by R2<->R5 bit-agreement):
//   A: a[j] = A[m = lane&15][k = (lane>>4)*8 + j]
//   B: b[j] = B[k = (lane>>4)*8 + j][n = lane&15]
//   D: d[r] = D[m = (lane>>4)*4 + r][n = lane&15]
__global__ __launch_bounds__(NTHR, 2) void lstm_v19(
    const float* __restrict__ x,
    const float* __restrict__ Wih0, const float* __restrict__ Whh0,
    const float* __restrict__ bih0, const float* __restrict__ bhh0,
    const float* __restrict__ Wih1, const float* __restrict__ Whh1,
    const float* __restrict__ bih1, const float* __restrict__ bhh1,
    const float* __restrict__ Wout, const float* __restrict__ bout,
    float* __restrict__ out,
    unsigned* bar,
    float* ring0,       // 2 slots [64][512] fp32 (h0)
    float* ring1,       // 2 slots [64][512] fp32 (h1)
    float* h1fin)       // 1 slot  (final h1, sys, for epilogue)
{
    const int tid  = threadIdx.x;
    const int wave = tid >> 6;
    const int lane = tid & 63;
    const int l15  = lane & 15;
    const int quad = lane >> 4;
    const int blk  = blockIdx.x;
    const int sel  = blk & 7;
    if (sel >= 4) return;              // idle half of the grid (XCDs 4-7)
    const int mt = sel;                // batch tile (4 x 16 rows), = XCD id
    const int jt = blk >> 3;           // column tile (32 x 16), worker id

    unsigned* f0  = bar + (0  + mt) * LINE;  // L0 flags (agent on fast path)
    unsigned* f1  = bar + (4  + mt) * LINE;  // L1 flags
    unsigned* fin = bar + (8  + mt) * LINE;  // per-group completion (sys)
    unsigned* xl  = bar + (12 + mt) * LINE;  // xcd verify table (sys)

    __shared__ float red0[8][4][4][64];   // L0 partials, one set per wave
    __shared__ float red1[8][4][4][64];   // L1 partials
    __shared__ int s_fast;

    // ---- XCD verification (once): group-uniform fast/slow decision ----
    unsigned xcc;
    asm volatile("s_getreg_b32 %0, hwreg(HW_REG_XCC_ID)" : "=s"(xcc));
    if (wave == 0) {
        if (lane == 0) st_sys_u(xl + jt, xcc + 1u);
        unsigned v;
        for (;;) {
            v = ld_sys_u(xl + (lane & 31));
            if (__all((int)(v != 0u))) break;
            __builtin_amdgcn_s_sleep(1);
        }
        const int f = __all((int)(v == xcc + 1u));
        if (lane == 0) s_fast = f;
    }
    __syncthreads();
    const bool fast = (s_fast != 0);

    // Combined biases: wave0 -> layer0, wave1 -> layer1 (cols jt*16 + l15).
    float bsi = 0.f, bsf = 0.f, bsg = 0.f, bso = 0.f;
    if (wave < 2) {
        const int j = jt * 16 + l15;
        const float* bi = (wave == 1) ? bih1 : bih0;
        const float* bh = (wave == 1) ? bhh1 : bhh0;
        bsi = bi[j]        + bh[j];
        bsf = bi[512 + j]  + bh[512 + j];
        bsg = bi[1024 + j] + bh[1024 + j];
        bso = bi[1536 + j] + bh[1536 + j];
    }

    // ---- weights into registers ----
    // L0: 18 chunks of K=32 over [x(0..63)|h0(0..511)]: waves 0,1 take 3,
    // waves 2-7 take 2.
    const int cb0 = (wave < 2) ? 3 * wave : 6 + (wave - 2) * 2;
    const int cn0 = (wave < 2) ? 3 : 2;
    half8 bf0[4][3];
    #pragma unroll
    for (int g = 0; g < 4; ++g) {
        const int n = g * 512 + jt * 16 + l15;   // gate row (i,f,g,o)
        #pragma unroll
        for (int cc = 0; cc < 3; ++cc) {
            if (cc < cn0) {
                const int c = cb0 + cc;
                const float* src = (c < 2)
                    ? (Wih0 + n * 64  + c * 32 + quad * 8)
                    : (Whh0 + n * 512 + (c - 2) * 32 + quad * 8);
                bf0[g][cc] = frag8(src);
            }
        }
    }
    // L1: 32 chunks over [h0(0..511)|h1(0..511)]: 4 per wave; waves 0-3 h0
    // side, waves 4-7 h1 side.
    half8 bf1[4][4];
    #pragma unroll
    for (int g = 0; g < 4; ++g) {
        const int n = g * 512 + jt * 16 + l15;
        #pragma unroll
        for (int cc = 0; cc < 4; ++cc) {
            const int c = wave * 4 + cc;          // 0..31
            const float* src = (c < 16)
                ? (Wih1 + n * 512 + c * 32 + quad * 8)
                : (Whh1 + n * 512 + (c - 16) * 32 + quad * 8);
            bf1[g][cc] = frag8(src);
        }
    }

    float cst0[4] = {0.f, 0.f, 0.f, 0.f};  // L0 cell state (wave0 only uses)
    float cst1[4] = {0.f, 0.f, 0.f, 0.f};  // L1 cell state (wave1 only uses)
    const int arow = mt * 16 + l15;

    for (int s = 0; s <= T_; ++s) {
        // phase1: overlapped group waits
        if (wave == 0) {
            if (fast) wait_agt(f0, (unsigned)s, lane);
            else      wait_sys(f0, (unsigned)s, lane);
        } else if (wave == 1) {
            if (fast) wait_agt(f1, (unsigned)s, lane);
            else      wait_sys(f1, (unsigned)s, lane);
        }
        __syncthreads();   // A

        // phase3: partials for both layers
        if (s < T_) {      // L0 step s: A = [x_s | h0[s-1]]
            floatx4 a0[4] = { {0.f,0.f,0.f,0.f}, {0.f,0.f,0.f,0.f},
                              {0.f,0.f,0.f,0.f}, {0.f,0.f,0.f,0.f} };
            const float* h0p = ring0 + ((s + 1) & 1) * SLOT + arow * H_; // slot (s-1)&1
            #pragma unroll
            for (int cc = 0; cc < 3; ++cc) {
                if (cc < cn0) {
                    const int c = cb0 + cc;
                    half8 a;
                    if (c < 2)     a = frag8(x + (arow * T_ + s) * DIN_ + c * 32 + quad * 8);
                    else if (fast) a = frag8_agt(h0p + (c - 2) * 32 + quad * 8);
                    else           a = frag8_sys(h0p + (c - 2) * 32 + quad * 8);
                    a0[0] = __builtin_amdgcn_mfma_f32_16x16x32_f16(a, bf0[0][cc], a0[0], 0, 0, 0);
                    a0[1] = __builtin_amdgcn_mfma_f32_16x16x32_f16(a, bf0[1][cc], a0[1], 0, 0, 0);
                    a0[2] = __builtin_amdgcn_mfma_f32_16x16x32_f16(a, bf0[2][cc], a0[2], 0, 0, 0);
                    a0[3] = __builtin_amdgcn_mfma_f32_16x16x32_f16(a, bf0[3][cc], a0[3], 0, 0, 0);
                }
            }
            #pragma unroll
            for (int g = 0; g < 4; ++g)
                #pragma unroll
                for (int r = 0; r < 4; ++r)
                    red0[wave][g][r][lane] = a0[g][r];
        }
        if (s >= 1) {      // L1 step tau=s-1: A = [h0[s-1] | h1[s-2]]
            floatx4 a1[4] = { {0.f,0.f,0.f,0.f}, {0.f,0.f,0.f,0.f},
                              {0.f,0.f,0.f,0.f}, {0.f,0.f,0.f,0.f} };
            const float* rb = (wave < 4)
                ? ring0 + ((s + 1) & 1) * SLOT + arow * H_   // h0[s-1], slot (s-1)&1
                : ring1 + (s & 1) * SLOT + arow * H_;        // h1[s-2], slot (s-2)&1
            const int cofs = (wave < 4) ? wave * 4 : wave * 4 - 16;
            #pragma unroll
            for (int cc = 0; cc < 4; ++cc) {
                const half8 a = fast ? frag8_agt(rb + (cofs + cc) * 32 + quad * 8)
                                     : frag8_sys(rb + (cofs + cc) * 32 + quad * 8);
                a1[0] = __builtin_amdgcn_mfma_f32_16x16x32_f16(a, bf1[0][cc], a1[0], 0, 0, 0);
                a1[1] = __builtin_amdgcn_mfma_f32_16x16x32_f16(a, bf1[1][cc], a1[1], 0, 0, 0);
                a1[2] = __builtin_amdgcn_mfma_f32_16x16x32_f16(a, bf1[2][cc], a1[2], 0, 0, 0);
                a1[3] = __builtin_amdgcn_mfma_f32_16x16x32_f16(a, bf1[3][cc], a1[3], 0, 0, 0);
            }
            #pragma unroll
            for (int g = 0; g < 4; ++g)
                #pragma unroll
                for (int r = 0; r < 4; ++r)
                    red1[wave][g][r][lane] = a1[g][r];
        }
        __syncthreads();   // B

        // phase5: concurrent finalize — wave0: L0, wave1: L1
        if (wave == 0) {
            if (s < T_) {
                float* hd = ring0 + (s & 1) * SLOT;
                #pragma unroll
                for (int r = 0; r < 4; ++r) {
                    float ai = 0.f, af = 0.f, ag = 0.f, ao = 0.f;
                    #pragma unroll
                    for (int w = 0; w < 8; ++w) {
                        ai += red0[w][0][r][lane];
                        af += red0[w][1][r][lane];
                        ag += red0[w][2][r][lane];
                        ao += red0[w][3][r][lane];
                    }
                    const float ig = sigf(ai + bsi);
                    const float fg = sigf(af + bsf);
                    const float gg = tanhf_(ag + bsg);
                    const float og = sigf(ao + bso);
                    const float cn = fg * cst0[r] + ig * gg;
                    cst0[r] = cn;
                    const float hv = og * tanhf_(cn);
                    const int idx = (mt * 16 + quad * 4 + r) * H_ + jt * 16 + l15;
                    if (fast) st_agt(hd + idx, hv); else st_sys(hd + idx, hv);
                }
            }
            asm volatile("s_waitcnt vmcnt(0)" ::: "memory");
            if (lane == 0) {
                if (fast) st_agt_u(f0 + jt, (unsigned)(s + 1));
                else      st_sys_u(f0 + jt, (unsigned)(s + 1));
            }
        } else if (wave == 1) {
            if (s >= 1) {
                const int tau = s - 1;
                float* hd = ring1 + (tau & 1) * SLOT;
                #pragma unroll
                for (int r = 0; r < 4; ++r) {
                    float ai = 0.f, af = 0.f, ag = 0.f, ao = 0.f;
                    #pragma unroll
                    for (int w = 0; w < 8; ++w) {
                        ai += red1[w][0][r][lane];
                        af += red1[w][1][r][lane];
                        ag += red1[w][2][r][lane];
                        ao += red1[w][3][r][lane];
                    }
                    const float ig = sigf(ai + bsi);
                    const float fg = sigf(af + bsf);
                    const float gg = tanhf_(ag + bsg);
                    const float og = sigf(ao + bso);
                    const float cn = fg * cst1[r] + ig * gg;
                    cst1[r] = cn;
                    const float hv = og * tanhf_(cn);
                    const int idx = (mt * 16 + quad * 4 + r) * H_ + jt * 16 + l15;
                    if (fast) st_agt(hd + idx, hv); else st_sys(hd + idx, hv);
                    if (tau == T_ - 1) st_sys(h1fin + idx, hv);  // epilogue copy
                }
            }
            asm volatile("s_waitcnt vmcnt(0)" ::: "memory");
            if (lane == 0) {
                if (fast) st_agt_u(f1 + jt, (unsigned)(s + 1));
                else      st_sys_u(f1 + jt, (unsigned)(s + 1));
            }
        }
    }

    // Group completion (h1fin drained by iter T_'s vmcnt(0) before this).
    if (wave == 1 && lane == 0) st_sys_u(fin + jt, 1u);

    // Wait for ALL 4 groups (epilogue reads h1fin rows from every mt).
    if (wave < 4) wait_sys(bar + (8 + wave) * LINE, 1u, lane);
    __syncthreads();

    // Epilogue: y[b][d] = h1_511[b][:] . Wout[d][:] + bout[d] (fp32 out).
    // 128 worker blocks x 512 threads = 65536 = 2048 outputs x 32 lanes.
    {
        const int wid = mt * 32 + jt;       // 0..127
        const int gid = wid * NTHR + tid;   // 0..65535
        const int o   = gid >> 5;           // 0..2047
        const int sub = gid & 31;
        const int ob  = o >> 5;
        const int od  = o & 31;
        float p = 0.f;
        const float* hb = h1fin + ob * H_ + sub * 16;
        const float* wb = Wout  + od * H_ + sub * 16;
        #pragma unroll
        for (int k = 0; k < 16; ++k) p += ld_sys_f(hb + k) * wb[k];
        p += __shfl_xor(p, 16);
        p += __shfl_xor(p, 8);
        p += __shfl_xor(p, 4);
        p += __shfl_xor(p, 2);
        p += __shfl_xor(p, 1);
        if (sub == 0) out[o] = p + bout[od];
    }
}

extern "C" void kernel_launch(void* const* d_in, const int* in_sizes, int n_in,
                              void* d_out, int out_size, void* d_ws, size_t ws_size,
                              hipStream_t stream) {
    (void)in_sizes; (void)n_in; (void)out_size; (void)ws_size;
    const float* x    = (const float*)d_in[0];
    const float* Wih0 = (const float*)d_in[1];
    const float* Whh0 = (const float*)d_in[2];
    const float* bih0 = (const float*)d_in[3];
    const float* bhh0 = (const float*)d_in[4];
    const float* Wih1 = (const float*)d_in[5];
    const float* Whh1 = (const float*)d_in[6];
    const float* bih1 = (const float*)d_in[7];
    const float* bhh1 = (const float*)d_in[8];
    const float* Wout = (const float*)d_in[9];
    const float* bout = (const float*)d_in[10];

    unsigned char* ws = (unsigned char*)d_ws;
    unsigned* bar = (unsigned*)ws;               // 8 KB: 16 lines of 256B
    float* ring0  = (float*)(ws + 8192);         // 2 slots x 128 KB (h0)
    float* ring1  = ring0 + 2 * SLOT;            // 2 slots x 128 KB (h1)
    float* h1fin  = ring1 + 2 * SLOT;            // 1 slot  x 128 KB
    // Zero flags + rings (slots holding h_{-1} must read 0).
    (void)hipMemsetAsync(ws, 0, 8192 + 5 * SLOT * 4, stream);

    lstm_v19<<<dim3(NBLK), dim3(NTHR), 0, stream>>>(
        x, Wih0, Whh0, bih0, bhh0, Wih1, Whh1, bih1, bhh1, Wout, bout,
        (float*)d_out, bar, ring0, ring1, h1fin);
}

// Round 7
// 5006.057 us; speedup vs baseline: 1.4649x; 1.4649x over previous
//
#include <hip/hip_runtime.h>

// LSTMDynamics v21: B=64, T=512, D_IN=64, H=512, D_OUT=32.
// v18 skewed two-block-per-(mt) structure + XCD pinning, restructured so NO
// sys-scope op sits on either layer's critical self-loop:
//   L0 loop: poll f0f(agent) -> agent h0 loads -> MFMA -> barrier -> wave0
//     reduce+gates -> agent h0 stores -> vmcnt(0) [drains agent + LAST step's
//     sys stores, ~free] -> publish f0f=s+1 (agent) + f0s=s (sys, certifies
//     h0[s-1]) -> [slack-cached f1s anti-dep check] -> issue sys h0[s] stores
//     UNDRAINED. MALL ack is off-loop.
//   L1 loop: waves2-3: poll f1f(agent) -> agent h1 loads -> MFMA -> barrier;
//     wave3: reduce+gates -> agent h1 store -> vmcnt(0) -> publish f1f/f1s.
//     waves0-1 run ONE ITER AHEAD post-barrier: slack-cached sys poll f0s ->
//     sys h0 loads -> MFMA -> park partials in parity-double-buffered LDS.
//     Sys h0 latency hides under a full period of pipeline slack.
// Mapping (v18 proven): sel=blk&7, layer=sel>>2, mt=sel&3, jt=blk>>3; round-
// robin dispatch pins group sel to XCD sel; runtime XCC_ID ballot verifies,
// sys fallback otherwise (protocol is scope-agnostic correct).
//
// Dependency algebra (f0f/f1f/f1s = completed iters+1; f0s = s means h0[s-1]
// sys-visible & drained):
//   L0 body s: all waves wait f0f>=s (peers thru s-1; covers 2-slot ring0a
//     anti-dep). Before sys store of slot s&3 (kills h0[s-4], read by L1
//     waves0-1 during L1 body s-4, done before their barrier s-3, which
//     precedes f1s=s-2): need f1s>=s-2 (guard s>=4, slack-cached).
//   L1 body s: waves2-3 wait f1f>=s (peers thru s-1 + 2-slot ring1 anti-dep);
//     wave3 consumes redA[par(s)] written by waves0-1 at body s-1 (barrier-
//     separated); waves0-1 post-barrier wait f0s>=s+1 then read h0[s] slot s&3.
//   Cycle check: L1@s <- L0@s+1 <- L1@s-1 : acyclic. Epilogue: sys h1fin +
//   per-group fin flags (drained by final vmcnt before publish).

#define T_    512
#define B_    64
#define H_    512
#define DIN_  64
#define NBLK  256
#define NTHR  256
#define SLOT  (B_ * H_)   // 32768 fp32 per ring slot, layout [b][k]
#define LINE  64          // dwords per flag line (256B)

typedef _Float16 half8  __attribute__((ext_vector_type(8)));
typedef float    floatx4 __attribute__((ext_vector_type(4)));

__device__ inline float sigf(float x) { return 1.f / (1.f + __expf(-x)); }
__device__ inline float tanhf_(float x) {
    if (x >  9.f) return  1.f;
    if (x < -9.f) return -1.f;
    const float e = __expf(2.f * x);
    return (e - 1.f) / (e + 1.f);
}
__device__ inline float4 ld4(const float* p) { return *(const float4*)p; }

__device__ inline half8 frag8(const float* p) {   // cached path (weights, x)
    const float4 a = ld4(p), b = ld4(p + 4);
    half8 r;
    r[0] = (_Float16)a.x; r[1] = (_Float16)a.y; r[2] = (_Float16)a.z; r[3] = (_Float16)a.w;
    r[4] = (_Float16)b.x; r[5] = (_Float16)b.y; r[6] = (_Float16)b.z; r[7] = (_Float16)b.w;
    return r;
}
__device__ inline half8 frag8_agt(const float* p) {
    float v[8];
    #pragma unroll
    for (int i = 0; i < 8; ++i)
        v[i] = __hip_atomic_load(p + i, __ATOMIC_RELAXED, __HIP_MEMORY_SCOPE_AGENT);
    half8 r;
    #pragma unroll
    for (int i = 0; i < 8; ++i) r[i] = (_Float16)v[i];
    return r;
}
__device__ inline half8 frag8_sys(const float* p) {
    float v[8];
    #pragma unroll
    for (int i = 0; i < 8; ++i)
        v[i] = __hip_atomic_load(p + i, __ATOMIC_RELAXED, __HIP_MEMORY_SCOPE_SYSTEM);
    half8 r;
    #pragma unroll
    for (int i = 0; i < 8; ++i) r[i] = (_Float16)v[i];
    return r;
}
__device__ inline float ld_sys_f(const float* p) {
    return __hip_atomic_load(p, __ATOMIC_RELAXED, __HIP_MEMORY_SCOPE_SYSTEM);
}
__device__ inline void st_sys(float* p, float v) {
    __hip_atomic_store(p, v, __ATOMIC_RELAXED, __HIP_MEMORY_SCOPE_SYSTEM);
}
__device__ inline void st_agt(float* p, float v) {
    __hip_atomic_store(p, v, __ATOMIC_RELAXED, __HIP_MEMORY_SCOPE_AGENT);
}
__device__ inline void st_sys_u(unsigned* p, unsigned v) {
    __hip_atomic_store(p, v, __ATOMIC_RELAXED, __HIP_MEMORY_SCOPE_SYSTEM);
}
__device__ inline void st_agt_u(unsigned* p, unsigned v) {
    __hip_atomic_store(p, v, __ATOMIC_RELAXED, __HIP_MEMORY_SCOPE_AGENT);
}
__device__ inline unsigned ld_sys_u(const unsigned* p) {
    return __hip_atomic_load(p, __ATOMIC_RELAXED, __HIP_MEMORY_SCOPE_SYSTEM);
}
__device__ inline unsigned ld_agt_u(const unsigned* p) {
    return __hip_atomic_load(p, __ATOMIC_RELAXED, __HIP_MEMORY_SCOPE_AGENT);
}

// Ballot flag waits (64 lanes read flags[lane&31]; exit when all >= tgt).
__device__ inline void wait_agt(unsigned* line, unsigned tgt, int lane) {
    for (;;) {
        const unsigned v = ld_agt_u(line + (lane & 31));
        if (__all((int)(v >= tgt))) return;
        __builtin_amdgcn_s_sleep(1);
    }
}
__device__ inline void wait_sys(unsigned* line, unsigned tgt, int lane) {
    for (;;) {
        const unsigned v = ld_sys_u(line + (lane & 31));
        if (__all((int)(v >= tgt))) return;
        __builtin_amdgcn_s_sleep(1);
    }
}
// Sys wait that returns the line MIN (for slack caching).
__device__ inline unsigned wait_min_sys(unsigned* line, unsigned tgt, int lane) {
    for (;;) {
        unsigned v = ld_sys_u(line + (lane & 31));
        #pragma unroll
        for (int o = 16; o >= 1; o >>= 1) {
            const unsigned w = (unsigned)__shfl_xor((int)v, o);
            v = v < w ? v : w;
        }
        if (v >= tgt) return v;
        __builtin_amdgcn_s_sleep(1);
    }
}

// MFMA 16x16x32 f16 fragment layout (proven by R2<->R5 bit-agreement):
//   A: a[j] = A[m = lane&15][k = (lane>>4)*8 + j]
//   B: b[j] = B[k = (lane>>4)*8 + j][n = lane&15]
//   D: d[r] = D[m = (lane>>4)*4 + r][n = lane&15]
__global__ __launch_bounds__(NTHR) void lstm_v21(
    const float* __restrict__ x,
    const float* __restrict__ Wih0, const float* __restrict__ Whh0,
    const float* __restrict__ bih0, const float* __restrict__ bhh0,
    const float* __restrict__ Wih1, const float* __restrict__ Whh1,
    const float* __restrict__ bih1, const float* __restrict__ bhh1,
    const float* __restrict__ Wout, const float* __restrict__ bout,
    float* __restrict__ out,
    unsigned* bar,
    float* ring0a,      // 2 slots (agent h0, L0 self-loop)
    float* ring0s,      // 4 slots (sys h0, read by L1)
    float* ring1,       // 2 slots (h1, agent)
    float* h1fin)       // 1 slot  (final h1, sys, epilogue)
{
    const int tid  = threadIdx.x;
    const int wave = tid >> 6;
    const int lane = tid & 63;
    const int l15  = lane & 15;
    const int quad = lane >> 4;
    const int blk  = blockIdx.x;
    const int sel  = blk & 7;
    const int layer = sel >> 2;
    const int mt    = sel & 3;
    const int jt    = blk >> 3;        // 0..31

    unsigned* f0f = bar + (0  + mt) * LINE;  // L0 agent flags
    unsigned* f0s = bar + (4  + mt) * LINE;  // L0 sys flags (delayed publish)
    unsigned* f1f = bar + (8  + mt) * LINE;  // L1 agent flags
    unsigned* f1s = bar + (12 + mt) * LINE;  // L1 sys flags
    unsigned* fin = bar + (16 + mt) * LINE;  // group completion (sys)
    unsigned* xl  = bar + (20 + sel) * LINE; // xcd verify (sys)

    // LDS: redA = L1 h0-side parity-buffered partials [par*2+w01][g][lane][r]
    //      (L0 reuses first 3 as its waves1-3 partials); redB = L1 wave2.
    __shared__ float redA[4][4][64][4];   // 16 KB
    __shared__ float redB[2][4][64][4];   // 8 KB
    __shared__ int s_fast;

    // ---- XCD verification (v18 proven) ----
    unsigned xcc;
    asm volatile("s_getreg_b32 %0, hwreg(HW_REG_XCC_ID)" : "=s"(xcc));
    if (wave == 0) {
        if (lane == 0) st_sys_u(xl + jt, xcc + 1u);
        unsigned v;
        for (;;) {
            v = ld_sys_u(xl + (lane & 31));
            if (__all((int)(v != 0u))) break;
            __builtin_amdgcn_s_sleep(1);
        }
        const int f = __all((int)(v == xcc + 1u));
        if (lane == 0) s_fast = f;
    }
    __syncthreads();
    const bool fast = (s_fast != 0);

    const int arow = mt * 16 + l15;

    if (layer == 0) {
        // ---- Layer 0 ----
        float bsi = 0.f, bsf = 0.f, bsg = 0.f, bso = 0.f;
        if (wave == 0) {
            const int j = jt * 16 + l15;
            bsi = bih0[j]        + bhh0[j];
            bsf = bih0[512 + j]  + bhh0[512 + j];
            bsg = bih0[1024 + j] + bhh0[1024 + j];
            bso = bih0[1536 + j] + bhh0[1536 + j];
        }
        // 18 K-chunks: waves 0,1 take 5; waves 2,3 take 4.
        const int cb = (wave < 2) ? wave * 5 : 10 + (wave - 2) * 4;
        const int cn = (wave < 2) ? 5 : 4;
        half8 bf[4][5];
        #pragma unroll
        for (int g = 0; g < 4; ++g) {
            const int n = g * 512 + jt * 16 + l15;
            #pragma unroll
            for (int cc = 0; cc < 5; ++cc) {
                if (cc < cn) {
                    const int c = cb + cc;
                    const float* src = (c < 2)
                        ? (Wih0 + n * 64  + c * 32 + quad * 8)
                        : (Whh0 + n * 512 + (c - 2) * 32 + quad * 8);
                    bf[g][cc] = frag8(src);
                }
            }
        }
        float cst[4] = {0.f, 0.f, 0.f, 0.f};
        unsigned cachedF1 = 0;

        for (int s = 0; s <= T_; ++s) {
            // All waves poll group flag directly (publish-after-barrier safe).
            if (s >= 1) {
                if (fast) wait_agt(f0f, (unsigned)s, lane);
                else      wait_sys(f0f, (unsigned)s, lane);
            }
            floatx4 acc[4] = { {0.f,0.f,0.f,0.f}, {0.f,0.f,0.f,0.f},
                               {0.f,0.f,0.f,0.f}, {0.f,0.f,0.f,0.f} };
            if (s < T_) {
                const float* h0p = ring0a + ((s + 1) & 1) * SLOT + arow * H_;
                #pragma unroll
                for (int cc = 0; cc < 5; ++cc) {
                    if (cc < cn) {
                        const int c = cb + cc;
                        half8 a;
                        if (c < 2)     a = frag8(x + (arow * T_ + s) * DIN_ + c * 32 + quad * 8);
                        else if (fast) a = frag8_agt(h0p + (c - 2) * 32 + quad * 8);
                        else           a = frag8_sys(h0p + (c - 2) * 32 + quad * 8);
                        acc[0] = __builtin_amdgcn_mfma_f32_16x16x32_f16(a, bf[0][cc], acc[0], 0, 0, 0);
                        acc[1] = __builtin_amdgcn_mfma_f32_16x16x32_f16(a, bf[1][cc], acc[1], 0, 0, 0);
                        acc[2] = __builtin_amdgcn_mfma_f32_16x16x32_f16(a, bf[2][cc], acc[2], 0, 0, 0);
                        acc[3] = __builtin_amdgcn_mfma_f32_16x16x32_f16(a, bf[3][cc], acc[3], 0, 0, 0);
                    }
                }
                if (wave != 0) {
                    #pragma unroll
                    for (int g = 0; g < 4; ++g)
                        *(float4*)redA[wave - 1][g][lane] = *(float4*)&acc[g];
                }
            }
            __syncthreads();
            if (wave == 0) {
                float hv[4];
                if (s < T_) {
                    float* da = ring0a + (s & 1) * SLOT;
                    #pragma unroll
                    for (int g = 0; g < 4; ++g) {
                        const float4 q0 = *(const float4*)redA[0][g][lane];
                        const float4 q1 = *(const float4*)redA[1][g][lane];
                        const float4 q2 = *(const float4*)redA[2][g][lane];
                        const float* p0 = (const float*)&q0;
                        const float* p1 = (const float*)&q1;
                        const float* p2 = (const float*)&q2;
                        #pragma unroll
                        for (int r = 0; r < 4; ++r)
                            acc[g][r] += p0[r] + p1[r] + p2[r];
                    }
                    #pragma unroll
                    for (int r = 0; r < 4; ++r) {
                        const float ig = sigf(acc[0][r] + bsi);
                        const float fg = sigf(acc[1][r] + bsf);
                        const float gg = tanhf_(acc[2][r] + bsg);
                        const float og = sigf(acc[3][r] + bso);
                        const float cn2 = fg * cst[r] + ig * gg;
                        cst[r] = cn2;
                        hv[r] = og * tanhf_(cn2);
                        const int idx = (mt * 16 + quad * 4 + r) * H_ + jt * 16 + l15;
                        if (fast) st_agt(da + idx, hv[r]); else st_sys(da + idx, hv[r]);
                    }
                }
                // Drain agent stores (+ last iter's sys stores, ~free).
                asm volatile("s_waitcnt vmcnt(0)" ::: "memory");
                if (lane == 0) {
                    if (fast) st_agt_u(f0f + jt, (unsigned)(s + 1));
                    else      st_sys_u(f0f + jt, (unsigned)(s + 1));
                    st_sys_u(f0s + jt, (unsigned)s);   // h0[s-1] sys-certified
                }
                if (s < T_) {
                    // Anti-dep for sys ring slot s&3 (kills h0[s-4]): f1s >= s-2.
                    if (s >= 4 && cachedF1 < (unsigned)(s - 2))
                        cachedF1 = wait_min_sys(f1s, (unsigned)(s - 2), lane);
                    float* ds = ring0s + (s & 3) * SLOT;
                    #pragma unroll
                    for (int r = 0; r < 4; ++r) {
                        const int idx = (mt * 16 + quad * 4 + r) * H_ + jt * 16 + l15;
                        st_sys(ds + idx, hv[r]);       // UNDRAINED — off-loop
                    }
                }
            }
        }
        // Final sys certify: h0[T_-1] (drained next vmcnt... ensure drained now)
        if (wave == 0) {
            asm volatile("s_waitcnt vmcnt(0)" ::: "memory");
            if (lane == 0) st_sys_u(f0s + jt, (unsigned)T_);
        }
    } else {
        // ---- Layer 1 ----  body s computes L1 step tau=s-1.
        float bsi = 0.f, bsf = 0.f, bsg = 0.f, bso = 0.f;
        if (wave == 3) {
            const int j = jt * 16 + l15;
            bsi = bih1[j]        + bhh1[j];
            bsf = bih1[512 + j]  + bhh1[512 + j];
            bsg = bih1[1024 + j] + bhh1[1024 + j];
            bso = bih1[1536 + j] + bhh1[1536 + j];
        }
        // 32 K-chunks: waves0-1 -> c 0..15 (h0 side), waves2-3 -> 16..31 (h1).
        half8 bf[4][8];
        #pragma unroll
        for (int g = 0; g < 4; ++g) {
            const int n = g * 512 + jt * 16 + l15;
            #pragma unroll
            for (int cc = 0; cc < 8; ++cc) {
                const int c = wave * 8 + cc;
                const float* src = (c < 16)
                    ? (Wih1 + n * 512 + c * 32 + quad * 8)
                    : (Whh1 + n * 512 + (c - 16) * 32 + quad * 8);
                bf[g][cc] = frag8(src);
            }
        }
        float cst[4] = {0.f, 0.f, 0.f, 0.f};
        unsigned cachedF0 = 0;

        for (int s = 0; s <= T_; ++s) {
            floatx4 acc[4] = { {0.f,0.f,0.f,0.f}, {0.f,0.f,0.f,0.f},
                               {0.f,0.f,0.f,0.f}, {0.f,0.f,0.f,0.f} };
            // Pre-barrier: h1 side (critical loop) — waves 2-3.
            if (wave >= 2 && s >= 1) {
                if (fast) wait_agt(f1f, (unsigned)s, lane);
                else      wait_sys(f1f, (unsigned)s, lane);
                const float* rb1 = ring1 + (s & 1) * SLOT + arow * H_; // h1[s-2]
                #pragma unroll
                for (int cc = 0; cc < 8; ++cc) {
                    const int c = wave * 8 + cc;       // 16..31
                    const half8 a = fast ? frag8_agt(rb1 + (c - 16) * 32 + quad * 8)
                                         : frag8_sys(rb1 + (c - 16) * 32 + quad * 8);
                    acc[0] = __builtin_amdgcn_mfma_f32_16x16x32_f16(a, bf[0][cc], acc[0], 0, 0, 0);
                    acc[1] = __builtin_amdgcn_mfma_f32_16x16x32_f16(a, bf[1][cc], acc[1], 0, 0, 0);
                    acc[2] = __builtin_amdgcn_mfma_f32_16x16x32_f16(a, bf[2][cc], acc[2], 0, 0, 0);
                    acc[3] = __builtin_amdgcn_mfma_f32_16x16x32_f16(a, bf[3][cc], acc[3], 0, 0, 0);
                }
                if (wave == 2) {
                    #pragma unroll
                    for (int g = 0; g < 4; ++g)
                        *(float4*)redB[s & 1][g][lane] = *(float4*)&acc[g];
                }
            }
            __syncthreads();
            // Post-barrier: wave3 finalizes step tau=s-1.
            if (wave == 3) {
                if (s >= 1) {
                    const int par = s & 1;
                    float* hd = ring1 + ((s - 1) & 1) * SLOT;
                    #pragma unroll
                    for (int g = 0; g < 4; ++g) {
                        const float4 q0 = *(const float4*)redA[par * 2 + 0][g][lane];
                        const float4 q1 = *(const float4*)redA[par * 2 + 1][g][lane];
                        const float4 q2 = *(const float4*)redB[par][g][lane];
                        const float* p0 = (const float*)&q0;
                        const float* p1 = (const float*)&q1;
                        const float* p2 = (const float*)&q2;
                        #pragma unroll
                        for (int r = 0; r < 4; ++r)
                            acc[g][r] += p0[r] + p1[r] + p2[r];
                    }
                    #pragma unroll
                    for (int r = 0; r < 4; ++r) {
                        const float ig = sigf(acc[0][r] + bsi);
                        const float fg = sigf(acc[1][r] + bsf);
                        const float gg = tanhf_(acc[2][r] + bsg);
                        const float og = sigf(acc[3][r] + bso);
                        const float cn2 = fg * cst[r] + ig * gg;
                        cst[r] = cn2;
                        const float hv = og * tanhf_(cn2);
                        const int idx = (mt * 16 + quad * 4 + r) * H_ + jt * 16 + l15;
                        if (fast) st_agt(hd + idx, hv); else st_sys(hd + idx, hv);
                        if (s == T_) st_sys(h1fin + idx, hv);
                    }
                }
                asm volatile("s_waitcnt vmcnt(0)" ::: "memory");
                if (lane == 0) {
                    if (fast) st_agt_u(f1f + jt, (unsigned)(s + 1));
                    else      st_sys_u(f1f + jt, (unsigned)(s + 1));
                    st_sys_u(f1s + jt, (unsigned)(s + 1));
                }
            }
            // Post-barrier: waves 0-1 pipeline h0 side for body s+1 (reads h0[s]).
            if (wave < 2 && s < T_) {
                if (cachedF0 < (unsigned)(s + 1))
                    cachedF0 = wait_min_sys(f0s, (unsigned)(s + 1), lane);
                const float* rb0 = ring0s + (s & 3) * SLOT + arow * H_;
                #pragma unroll
                for (int cc = 0; cc < 8; ++cc) {
                    const int c = wave * 8 + cc;       // 0..15
                    const half8 a = frag8_sys(rb0 + c * 32 + quad * 8);
                    acc[0] = __builtin_amdgcn_mfma_f32_16x16x32_f16(a, bf[0][cc], acc[0], 0, 0, 0);
                    acc[1] = __builtin_amdgcn_mfma_f32_16x16x32_f16(a, bf[1][cc], acc[1], 0, 0, 0);
                    acc[2] = __builtin_amdgcn_mfma_f32_16x16x32_f16(a, bf[2][cc], acc[2], 0, 0, 0);
                    acc[3] = __builtin_amdgcn_mfma_f32_16x16x32_f16(a, bf[3][cc], acc[3], 0, 0, 0);
                }
                const int par1 = (s + 1) & 1;
                #pragma unroll
                for (int g = 0; g < 4; ++g)
                    *(float4*)redA[par1 * 2 + wave][g][lane] = *(float4*)&acc[g];
            }
        }
        if (wave == 3 && lane == 0) st_sys_u(fin + jt, 1u);  // h1fin drained above
    }

    // Wait for ALL groups' completion (epilogue reads h1fin from every mt).
    if (wave < 4) wait_sys(bar + (16 + wave) * LINE, 1u, lane);
    __syncthreads();

    // Epilogue: y[b][d] = h1_511[b][:] . Wout[d][:] + bout[d] (fp32 out).
    {
        const int gid = blk * NTHR + tid;   // 0..65535
        const int o   = gid >> 5;           // 0..2047
        const int sub = gid & 31;
        const int ob  = o >> 5;
        const int od  = o & 31;
        float p = 0.f;
        const float* hb = h1fin + ob * H_ + sub * 16;
        const float* wb = Wout  + od * H_ + sub * 16;
        #pragma unroll
        for (int k = 0; k < 16; ++k) p += ld_sys_f(hb + k) * wb[k];
        p += __shfl_xor(p, 16);
        p += __shfl_xor(p, 8);
        p += __shfl_xor(p, 4);
        p += __shfl_xor(p, 2);
        p += __shfl_xor(p, 1);
        if (sub == 0) out[o] = p + bout[od];
    }
}

extern "C" void kernel_launch(void* const* d_in, const int* in_sizes, int n_in,
                              void* d_out, int out_size, void* d_ws, size_t ws_size,
                              hipStream_t stream) {
    (void)in_sizes; (void)n_in; (void)out_size; (void)ws_size;
    const float* x    = (const float*)d_in[0];
    const float* Wih0 = (const float*)d_in[1];
    const float* Whh0 = (const float*)d_in[2];
    const float* bih0 = (const float*)d_in[3];
    const float* bhh0 = (const float*)d_in[4];
    const float* Wih1 = (const float*)d_in[5];
    const float* Whh1 = (const float*)d_in[6];
    const float* bih1 = (const float*)d_in[7];
    const float* bhh1 = (const float*)d_in[8];
    const float* Wout = (const float*)d_in[9];
    const float* bout = (const float*)d_in[10];

    unsigned char* ws = (unsigned char*)d_ws;
    unsigned* bar = (unsigned*)ws;               // 8 KB: 28 lines of 256B
    float* ring0a = (float*)(ws + 8192);         // 2 slots (agent h0)
    float* ring0s = ring0a + 2 * SLOT;           // 4 slots (sys h0)
    float* ring1  = ring0s + 4 * SLOT;           // 2 slots (h1)
    float* h1fin  = ring1  + 2 * SLOT;           // 1 slot
    (void)hipMemsetAsync(ws, 0, 8192 + 9 * SLOT * 4, stream);

    lstm_v21<<<dim3(NBLK), dim3(NTHR), 0, stream>>>(
        x, Wih0, Whh0, bih0, bhh0, Wih1, Whh1, bih1, bhh1, Wout, bout,
        (float*)d_out, bar, ring0a, ring0s, ring1, h1fin);
}

// Round 9
// 4480.885 us; speedup vs baseline: 1.6366x; 1.1172x over previous
//
#include <hip/hip_runtime.h>

// LSTMDynamics v22b: B=64, T=512, D_IN=64, H=512, D_OUT=32.
// v21 (proven: 4710us kernel) with ONE change: active-spin waits.
// (v22 resubmit — previous round's container failed before running.)
//
// Clock hypothesis: v21's waves sleep ~95% of the time (s_sleep spin); at
// 1.8% MfmaUtil / 4% VALUBusy the DPM governor parks SCLK low, inflating
// every L2 RT / store-ack / barrier hop ~3-5x — which explains why v17-v21's
// protocol surgery each gained only 2-6% while the cycle model predicts
// ~1.5-2us/step. v22 replaces s_sleep(1) (64 idle cycles) in the critical
// wait loops with a 16-deep dependent integer-FMA burst (~64 BUSY cycles,
// kept live via asm). Same backoff, same polling rate, same protocol,
// same arithmetic — but every CU issues continuously, holding clocks up.
//
// Everything else is v21 verbatim (see its header for the dependency
// algebra: agent self-loops, delayed sys publication, pipelined L1 h0-side,
// XCD pinning with runtime XCC_ID ballot + sys fallback).

#define T_    512
#define B_    64
#define H_    512
#define DIN_  64
#define NBLK  256
#define NTHR  256
#define SLOT  (B_ * H_)   // 32768 fp32 per ring slot, layout [b][k]
#define LINE  64          // dwords per flag line (256B)

typedef _Float16 half8  __attribute__((ext_vector_type(8)));
typedef float    floatx4 __attribute__((ext_vector_type(4)));

__device__ inline float sigf(float x) { return 1.f / (1.f + __expf(-x)); }
__device__ inline float tanhf_(float x) {
    if (x >  9.f) return  1.f;
    if (x < -9.f) return -1.f;
    const float e = __expf(2.f * x);
    return (e - 1.f) / (e + 1.f);
}
__device__ inline float4 ld4(const float* p) { return *(const float4*)p; }

__device__ inline half8 frag8(const float* p) {   // cached path (weights, x)
    const float4 a = ld4(p), b = ld4(p + 4);
    half8 r;
    r[0] = (_Float16)a.x; r[1] = (_Float16)a.y; r[2] = (_Float16)a.z; r[3] = (_Float16)a.w;
    r[4] = (_Float16)b.x; r[5] = (_Float16)b.y; r[6] = (_Float16)b.z; r[7] = (_Float16)b.w;
    return r;
}
__device__ inline half8 frag8_agt(const float* p) {
    float v[8];
    #pragma unroll
    for (int i = 0; i < 8; ++i)
        v[i] = __hip_atomic_load(p + i, __ATOMIC_RELAXED, __HIP_MEMORY_SCOPE_AGENT);
    half8 r;
    #pragma unroll
    for (int i = 0; i < 8; ++i) r[i] = (_Float16)v[i];
    return r;
}
__device__ inline half8 frag8_sys(const float* p) {
    float v[8];
    #pragma unroll
    for (int i = 0; i < 8; ++i)
        v[i] = __hip_atomic_load(p + i, __ATOMIC_RELAXED, __HIP_MEMORY_SCOPE_SYSTEM);
    half8 r;
    #pragma unroll
    for (int i = 0; i < 8; ++i) r[i] = (_Float16)v[i];
    return r;
}
__device__ inline float ld_sys_f(const float* p) {
    return __hip_atomic_load(p, __ATOMIC_RELAXED, __HIP_MEMORY_SCOPE_SYSTEM);
}
__device__ inline void st_sys(float* p, float v) {
    __hip_atomic_store(p, v, __ATOMIC_RELAXED, __HIP_MEMORY_SCOPE_SYSTEM);
}
__device__ inline void st_agt(float* p, float v) {
    __hip_atomic_store(p, v, __ATOMIC_RELAXED, __HIP_MEMORY_SCOPE_AGENT);
}
__device__ inline void st_sys_u(unsigned* p, unsigned v) {
    __hip_atomic_store(p, v, __ATOMIC_RELAXED, __HIP_MEMORY_SCOPE_SYSTEM);
}
__device__ inline void st_agt_u(unsigned* p, unsigned v) {
    __hip_atomic_store(p, v, __ATOMIC_RELAXED, __HIP_MEMORY_SCOPE_AGENT);
}
__device__ inline unsigned ld_sys_u(const unsigned* p) {
    return __hip_atomic_load(p, __ATOMIC_RELAXED, __HIP_MEMORY_SCOPE_SYSTEM);
}
__device__ inline unsigned ld_agt_u(const unsigned* p) {
    return __hip_atomic_load(p, __ATOMIC_RELAXED, __HIP_MEMORY_SCOPE_AGENT);
}

// Keep-alive backoff: ~64 BUSY cycles (16-deep dependent int FMA), kept
// live so the compiler can't delete or hoist it. Replaces s_sleep(1).
__device__ inline unsigned spin_pause(unsigned x) {
    #pragma unroll
    for (int i = 0; i < 16; ++i) x = x * 1664525u + 1013904223u;
    asm volatile("" : "+v"(x));
    return x;
}

// Ballot flag waits (64 lanes read flags[lane&31]; exit when all >= tgt).
__device__ inline void wait_agt(unsigned* line, unsigned tgt, int lane) {
    unsigned junk = (unsigned)lane;
    for (;;) {
        const unsigned v = ld_agt_u(line + (lane & 31));
        if (__all((int)(v >= tgt))) break;
        junk = spin_pause(junk);
    }
    asm volatile("" :: "v"(junk));
}
__device__ inline void wait_sys(unsigned* line, unsigned tgt, int lane) {
    unsigned junk = (unsigned)lane;
    for (;;) {
        const unsigned v = ld_sys_u(line + (lane & 31));
        if (__all((int)(v >= tgt))) break;
        junk = spin_pause(junk);
    }
    asm volatile("" :: "v"(junk));
}
// Sys wait that returns the line MIN (for slack caching).
__device__ inline unsigned wait_min_sys(unsigned* line, unsigned tgt, int lane) {
    unsigned junk = (unsigned)lane;
    for (;;) {
        unsigned v = ld_sys_u(line + (lane & 31));
        #pragma unroll
        for (int o = 16; o >= 1; o >>= 1) {
            const unsigned w = (unsigned)__shfl_xor((int)v, o);
            v = v < w ? v : w;
        }
        if (v >= tgt) { asm volatile("" :: "v"(junk)); return v; }
        junk = spin_pause(junk);
    }
}

// MFMA 16x16x32 f16 fragment layout (proven by R2<->R5 bit-agreement):
//   A: a[j] = A[m = lane&15][k = (lane>>4)*8 + j]
//   B: b[j] = B[k = (lane>>4)*8 + j][n = lane&15]
//   D: d[r] = D[m = (lane>>4)*4 + r][n = lane&15]
__global__ __launch_bounds__(NTHR) void lstm_v22(
    const float* __restrict__ x,
    const float* __restrict__ Wih0, const float* __restrict__ Whh0,
    const float* __restrict__ bih0, const float* __restrict__ bhh0,
    const float* __restrict__ Wih1, const float* __restrict__ Whh1,
    const float* __restrict__ bih1, const float* __restrict__ bhh1,
    const float* __restrict__ Wout, const float* __restrict__ bout,
    float* __restrict__ out,
    unsigned* bar,
    float* ring0a,      // 2 slots (agent h0, L0 self-loop)
    float* ring0s,      // 4 slots (sys h0, read by L1)
    float* ring1,       // 2 slots (h1, agent)
    float* h1fin)       // 1 slot  (final h1, sys, epilogue)
{
    const int tid  = threadIdx.x;
    const int wave = tid >> 6;
    const int lane = tid & 63;
    const int l15  = lane & 15;
    const int quad = lane >> 4;
    const int blk  = blockIdx.x;
    const int sel  = blk & 7;
    const int layer = sel >> 2;
    const int mt    = sel & 3;
    const int jt    = blk >> 3;        // 0..31

    unsigned* f0f = bar + (0  + mt) * LINE;  // L0 agent flags
    unsigned* f0s = bar + (4  + mt) * LINE;  // L0 sys flags (delayed publish)
    unsigned* f1f = bar + (8  + mt) * LINE;  // L1 agent flags
    unsigned* f1s = bar + (12 + mt) * LINE;  // L1 sys flags
    unsigned* fin = bar + (16 + mt) * LINE;  // group completion (sys)
    unsigned* xl  = bar + (20 + sel) * LINE; // xcd verify (sys)

    __shared__ float redA[4][4][64][4];   // 16 KB
    __shared__ float redB[2][4][64][4];   // 8 KB
    __shared__ int s_fast;

    // ---- XCD verification (v18 proven) ----
    unsigned xcc;
    asm volatile("s_getreg_b32 %0, hwreg(HW_REG_XCC_ID)" : "=s"(xcc));
    if (wave == 0) {
        if (lane == 0) st_sys_u(xl + jt, xcc + 1u);
        unsigned v;
        for (;;) {
            v = ld_sys_u(xl + (lane & 31));
            if (__all((int)(v != 0u))) break;
            __builtin_amdgcn_s_sleep(1);
        }
        const int f = __all((int)(v == xcc + 1u));
        if (lane == 0) s_fast = f;
    }
    __syncthreads();
    const bool fast = (s_fast != 0);

    const int arow = mt * 16 + l15;

    if (layer == 0) {
        // ---- Layer 0 ----
        float bsi = 0.f, bsf = 0.f, bsg = 0.f, bso = 0.f;
        if (wave == 0) {
            const int j = jt * 16 + l15;
            bsi = bih0[j]        + bhh0[j];
            bsf = bih0[512 + j]  + bhh0[512 + j];
            bsg = bih0[1024 + j] + bhh0[1024 + j];
            bso = bih0[1536 + j] + bhh0[1536 + j];
        }
        // 18 K-chunks: waves 0,1 take 5; waves 2,3 take 4.
        const int cb = (wave < 2) ? wave * 5 : 10 + (wave - 2) * 4;
        const int cn = (wave < 2) ? 5 : 4;
        half8 bf[4][5];
        #pragma unroll
        for (int g = 0; g < 4; ++g) {
            const int n = g * 512 + jt * 16 + l15;
            #pragma unroll
            for (int cc = 0; cc < 5; ++cc) {
                if (cc < cn) {
                    const int c = cb + cc;
                    const float* src = (c < 2)
                        ? (Wih0 + n * 64  + c * 32 + quad * 8)
                        : (Whh0 + n * 512 + (c - 2) * 32 + quad * 8);
                    bf[g][cc] = frag8(src);
                }
            }
        }
        float cst[4] = {0.f, 0.f, 0.f, 0.f};
        unsigned cachedF1 = 0;

        for (int s = 0; s <= T_; ++s) {
            if (s >= 1) {
                if (fast) wait_agt(f0f, (unsigned)s, lane);
                else      wait_sys(f0f, (unsigned)s, lane);
            }
            floatx4 acc[4] = { {0.f,0.f,0.f,0.f}, {0.f,0.f,0.f,0.f},
                               {0.f,0.f,0.f,0.f}, {0.f,0.f,0.f,0.f} };
            if (s < T_) {
                const float* h0p = ring0a + ((s + 1) & 1) * SLOT + arow * H_;
                #pragma unroll
                for (int cc = 0; cc < 5; ++cc) {
                    if (cc < cn) {
                        const int c = cb + cc;
                        half8 a;
                        if (c < 2)     a = frag8(x + (arow * T_ + s) * DIN_ + c * 32 + quad * 8);
                        else if (fast) a = frag8_agt(h0p + (c - 2) * 32 + quad * 8);
                        else           a = frag8_sys(h0p + (c - 2) * 32 + quad * 8);
                        acc[0] = __builtin_amdgcn_mfma_f32_16x16x32_f16(a, bf[0][cc], acc[0], 0, 0, 0);
                        acc[1] = __builtin_amdgcn_mfma_f32_16x16x32_f16(a, bf[1][cc], acc[1], 0, 0, 0);
                        acc[2] = __builtin_amdgcn_mfma_f32_16x16x32_f16(a, bf[2][cc], acc[2], 0, 0, 0);
                        acc[3] = __builtin_amdgcn_mfma_f32_16x16x32_f16(a, bf[3][cc], acc[3], 0, 0, 0);
                    }
                }
                if (wave != 0) {
                    #pragma unroll
                    for (int g = 0; g < 4; ++g)
                        *(float4*)redA[wave - 1][g][lane] = *(float4*)&acc[g];
                }
            }
            __syncthreads();
            if (wave == 0) {
                float hv[4];
                if (s < T_) {
                    float* da = ring0a + (s & 1) * SLOT;
                    #pragma unroll
                    for (int g = 0; g < 4; ++g) {
                        const float4 q0 = *(const float4*)redA[0][g][lane];
                        const float4 q1 = *(const float4*)redA[1][g][lane];
                        const float4 q2 = *(const float4*)redA[2][g][lane];
                        const float* p0 = (const float*)&q0;
                        const float* p1 = (const float*)&q1;
                        const float* p2 = (const float*)&q2;
                        #pragma unroll
                        for (int r = 0; r < 4; ++r)
                            acc[g][r] += p0[r] + p1[r] + p2[r];
                    }
                    #pragma unroll
                    for (int r = 0; r < 4; ++r) {
                        const float ig = sigf(acc[0][r] + bsi);
                        const float fg = sigf(acc[1][r] + bsf);
                        const float gg = tanhf_(acc[2][r] + bsg);
                        const float og = sigf(acc[3][r] + bso);
                        const float cn2 = fg * cst[r] + ig * gg;
                        cst[r] = cn2;
                        hv[r] = og * tanhf_(cn2);
                        const int idx = (mt * 16 + quad * 4 + r) * H_ + jt * 16 + l15;
                        if (fast) st_agt(da + idx, hv[r]); else st_sys(da + idx, hv[r]);
                    }
                }
                asm volatile("s_waitcnt vmcnt(0)" ::: "memory");
                if (lane == 0) {
                    if (fast) st_agt_u(f0f + jt, (unsigned)(s + 1));
                    else      st_sys_u(f0f + jt, (unsigned)(s + 1));
                    st_sys_u(f0s + jt, (unsigned)s);   // h0[s-1] sys-certified
                }
                if (s < T_) {
                    if (s >= 4 && cachedF1 < (unsigned)(s - 2))
                        cachedF1 = wait_min_sys(f1s, (unsigned)(s - 2), lane);
                    float* ds = ring0s + (s & 3) * SLOT;
                    #pragma unroll
                    for (int r = 0; r < 4; ++r) {
                        const int idx = (mt * 16 + quad * 4 + r) * H_ + jt * 16 + l15;
                        st_sys(ds + idx, hv[r]);       // UNDRAINED — off-loop
                    }
                }
            }
        }
        if (wave == 0) {
            asm volatile("s_waitcnt vmcnt(0)" ::: "memory");
            if (lane == 0) st_sys_u(f0s + jt, (unsigned)T_);
        }
    } else {
        // ---- Layer 1 ----  body s computes L1 step tau=s-1.
        float bsi = 0.f, bsf = 0.f, bsg = 0.f, bso = 0.f;
        if (wave == 3) {
            const int j = jt * 16 + l15;
            bsi = bih1[j]        + bhh1[j];
            bsf = bih1[512 + j]  + bhh1[512 + j];
            bsg = bih1[1024 + j] + bhh1[1024 + j];
            bso = bih1[1536 + j] + bhh1[1536 + j];
        }
        half8 bf[4][8];
        #pragma unroll
        for (int g = 0; g < 4; ++g) {
            const int n = g * 512 + jt * 16 + l15;
            #pragma unroll
            for (int cc = 0; cc < 8; ++cc) {
                const int c = wave * 8 + cc;
                const float* src = (c < 16)
                    ? (Wih1 + n * 512 + c * 32 + quad * 8)
                    : (Whh1 + n * 512 + (c - 16) * 32 + quad * 8);
                bf[g][cc] = frag8(src);
            }
        }
        float cst[4] = {0.f, 0.f, 0.f, 0.f};
        unsigned cachedF0 = 0;

        for (int s = 0; s <= T_; ++s) {
            floatx4 acc[4] = { {0.f,0.f,0.f,0.f}, {0.f,0.f,0.f,0.f},
                               {0.f,0.f,0.f,0.f}, {0.f,0.f,0.f,0.f} };
            if (wave >= 2 && s >= 1) {
                if (fast) wait_agt(f1f, (unsigned)s, lane);
                else      wait_sys(f1f, (unsigned)s, lane);
                const float* rb1 = ring1 + (s & 1) * SLOT + arow * H_; // h1[s-2]
                #pragma unroll
                for (int cc = 0; cc < 8; ++cc) {
                    const int c = wave * 8 + cc;       // 16..31
                    const half8 a = fast ? frag8_agt(rb1 + (c - 16) * 32 + quad * 8)
                                         : frag8_sys(rb1 + (c - 16) * 32 + quad * 8);
                    acc[0] = __builtin_amdgcn_mfma_f32_16x16x32_f16(a, bf[0][cc], acc[0], 0, 0, 0);
                    acc[1] = __builtin_amdgcn_mfma_f32_16x16x32_f16(a, bf[1][cc], acc[1], 0, 0, 0);
                    acc[2] = __builtin_amdgcn_mfma_f32_16x16x32_f16(a, bf[2][cc], acc[2], 0, 0, 0);
                    acc[3] = __builtin_amdgcn_mfma_f32_16x16x32_f16(a, bf[3][cc], acc[3], 0, 0, 0);
                }
                if (wave == 2) {
                    #pragma unroll
                    for (int g = 0; g < 4; ++g)
                        *(float4*)redB[s & 1][g][lane] = *(float4*)&acc[g];
                }
            }
            __syncthreads();
            if (wave == 3) {
                if (s >= 1) {
                    const int par = s & 1;
                    float* hd = ring1 + ((s - 1) & 1) * SLOT;
                    #pragma unroll
                    for (int g = 0; g < 4; ++g) {
                        const float4 q0 = *(const float4*)redA[par * 2 + 0][g][lane];
                        const float4 q1 = *(const float4*)redA[par * 2 + 1][g][lane];
                        const float4 q2 = *(const float4*)redB[par][g][lane];
                        const float* p0 = (const float*)&q0;
                        const float* p1 = (const float*)&q1;
                        const float* p2 = (const float*)&q2;
                        #pragma unroll
                        for (int r = 0; r < 4; ++r)
                            acc[g][r] += p0[r] + p1[r] + p2[r];
                    }
                    #pragma unroll
                    for (int r = 0; r < 4; ++r) {
                        const float ig = sigf(acc[0][r] + bsi);
                        const float fg = sigf(acc[1][r] + bsf);
                        const float gg = tanhf_(acc[2][r] + bsg);
                        const float og = sigf(acc[3][r] + bso);
                        const float cn2 = fg * cst[r] + ig * gg;
                        cst[r] = cn2;
                        const float hv = og * tanhf_(cn2);
                        const int idx = (mt * 16 + quad * 4 + r) * H_ + jt * 16 + l15;
                        if (fast) st_agt(hd + idx, hv); else st_sys(hd + idx, hv);
                        if (s == T_) st_sys(h1fin + idx, hv);
                    }
                }
                asm volatile("s_waitcnt vmcnt(0)" ::: "memory");
                if (lane == 0) {
                    if (fast) st_agt_u(f1f + jt, (unsigned)(s + 1));
                    else      st_sys_u(f1f + jt, (unsigned)(s + 1));
                    st_sys_u(f1s + jt, (unsigned)(s + 1));
                }
            }
            if (wave < 2 && s < T_) {
                if (cachedF0 < (unsigned)(s + 1))
                    cachedF0 = wait_min_sys(f0s, (unsigned)(s + 1), lane);
                const float* rb0 = ring0s + (s & 3) * SLOT + arow * H_;
                #pragma unroll
                for (int cc = 0; cc < 8; ++cc) {
                    const int c = wave * 8 + cc;       // 0..15
                    const half8 a = frag8_sys(rb0 + c * 32 + quad * 8);
                    acc[0] = __builtin_amdgcn_mfma_f32_16x16x32_f16(a, bf[0][cc], acc[0], 0, 0, 0);
                    acc[1] = __builtin_amdgcn_mfma_f32_16x16x32_f16(a, bf[1][cc], acc[1], 0, 0, 0);
                    acc[2] = __builtin_amdgcn_mfma_f32_16x16x32_f16(a, bf[2][cc], acc[2], 0, 0, 0);
                    acc[3] = __builtin_amdgcn_mfma_f32_16x16x32_f16(a, bf[3][cc], acc[3], 0, 0, 0);
                }
                const int par1 = (s + 1) & 1;
                #pragma unroll
                for (int g = 0; g < 4; ++g)
                    *(float4*)redA[par1 * 2 + wave][g][lane] = *(float4*)&acc[g];
            }
        }
        if (wave == 3 && lane == 0) st_sys_u(fin + jt, 1u);  // h1fin drained above
    }

    // Wait for ALL groups' completion (epilogue reads h1fin from every mt).
    if (wave < 4) wait_sys(bar + (16 + wave) * LINE, 1u, lane);
    __syncthreads();

    // Epilogue: y[b][d] = h1_511[b][:] . Wout[d][:] + bout[d] (fp32 out).
    {
        const int gid = blk * NTHR + tid;   // 0..65535
        const int o   = gid >> 5;           // 0..2047
        const int sub = gid & 31;
        const int ob  = o >> 5;
        const int od  = o & 31;
        float p = 0.f;
        const float* hb = h1fin + ob * H_ + sub * 16;
        const float* wb = Wout  + od * H_ + sub * 16;
        #pragma unroll
        for (int k = 0; k < 16; ++k) p += ld_sys_f(hb + k) * wb[k];
        p += __shfl_xor(p, 16);
        p += __shfl_xor(p, 8);
        p += __shfl_xor(p, 4);
        p += __shfl_xor(p, 2);
        p += __shfl_xor(p, 1);
        if (sub == 0) out[o] = p + bout[od];
    }
}

extern "C" void kernel_launch(void* const* d_in, const int* in_sizes, int n_in,
                              void* d_out, int out_size, void* d_ws, size_t ws_size,
                              hipStream_t stream) {
    (void)in_sizes; (void)n_in; (void)out_size; (void)ws_size;
    const float* x    = (const float*)d_in[0];
    const float* Wih0 = (const float*)d_in[1];
    const float* Whh0 = (const float*)d_in[2];
    const float* bih0 = (const float*)d_in[3];
    const float* bhh0 = (const float*)d_in[4];
    const float* Wih1 = (const float*)d_in[5];
    const float* Whh1 = (const float*)d_in[6];
    const float* bih1 = (const float*)d_in[7];
    const float* bhh1 = (const float*)d_in[8];
    const float* Wout = (const float*)d_in[9];
    const float* bout = (const float*)d_in[10];

    unsigned char* ws = (unsigned char*)d_ws;
    unsigned* bar = (unsigned*)ws;               // 8 KB: 28 lines of 256B
    float* ring0a = (float*)(ws + 8192);         // 2 slots (agent h0)
    float* ring0s = ring0a + 2 * SLOT;           // 4 slots (sys h0)
    float* ring1  = ring0s + 4 * SLOT;           // 2 slots (h1)
    float* h1fin  = ring1  + 2 * SLOT;           // 1 slot
    (void)hipMemsetAsync(ws, 0, 8192 + 9 * SLOT * 4, stream);

    lstm_v22<<<dim3(NBLK), dim3(NTHR), 0, stream>>>(
        x, Wih0, Whh0, bih0, bhh0, Wih1, Whh1, bih1, bhh1, Wout, bout,
        (float*)d_out, bar, ring0a, ring0s, ring1, h1fin);
}